// Round 6
// baseline (375.236 us; speedup 1.0000x reference)
//
#include <hip/hip_runtime.h>

// Chamfer loss: B=4, N=M=8192, D=3, fp32 in, scalar fp32 out.
// loss = mean_n min_m ||x_n-y_m||^2 + mean_m min_n ||...||^2 + lambda*bpp
//
// R5: v_pk_fma_f32 measured HALF-RATE (R3/R4: VALUBusy*dur == instrs at
// 4cy/pk) -> VALU floor is 3.5 scalar-slots/pair = 23.9us. Remaining
// ~20us of the pinned 44.8us matches per-CU LDS writeback time of the
// broadcast ds_read_b128 stream (16B/lane writeback isn't discounted
// for broadcast). Fixes: XR 8->16 (halves LDS instrs per pair),
// YC 256->128 (grid 2048, 8 blocks/CU = 4 waves/SIMD for VALU<->LDS
// cross-wave overlap), launch_bounds(128,4) to cap VGPR at 128.

typedef float v2f __attribute__((ext_vector_type(2)));
typedef float v4f __attribute__((ext_vector_type(4)));

#define NPTS    8192
#define NB      4
#define NPTOT   (NB * NPTS)         // 32768 points per cloud
#define NTHR    128
#define XR      16                  // x points per thread
#define XPB     (NTHR * XR)         // 2048 x per block
#define XTILES  (NPTS / XPB)        // 4
#define YC      128                 // y chunk staged in LDS
#define YCHUNKS (NPTS / YC)         // 64
#define GRID    (2 * NB * XTILES * YCHUNKS)   // 2048
#define RBLK    128                 // reduce stage-1 blocks

__device__ __forceinline__ int f2key(float f) {
    int i = __float_as_int(f);
    return i >= 0 ? i : (i ^ 0x7FFFFFFF);
}
__device__ __forceinline__ float key2f(int k) {
    return __int_as_float(k >= 0 ? k : (k ^ 0x7FFFFFFF));
}

__global__ __launch_bounds__(256) void init_min(int* mins) {
    int i = blockIdx.x * 256 + threadIdx.x;
    if (i < 2 * NPTOT) mins[i] = 0x7F800000;
}

#define LOADG(G, g)                                   \
    G##x = *(const v4f*)&lyx[4 * (g)];                \
    G##y = *(const v4f*)&lyy[4 * (g)];                \
    G##z = *(const v4f*)&lyz[4 * (g)];                \
    G##w = *(const v4f*)&lyw[4 * (g)];

#define PAIRSTEP(yx, yy, yz, yw)                                   \
    {                                                              \
        v2f _yx = (yx), _yy = (yy), _yz = (yz), _yw = (yw);        \
        _Pragma("unroll")                                          \
        for (int k = 0; k < XR; k++) {                             \
            v2f d = __builtin_elementwise_fma(xs[k], _yx, _yw);    \
            d = __builtin_elementwise_fma(ys[k], _yy, d);          \
            d = __builtin_elementwise_fma(zs[k], _yz, d);          \
            mn[k] = fminf(fminf(d.x, d.y), mn[k]);                 \
        }                                                          \
    }

#define COMPUTEG(G)                                                      \
    PAIRSTEP(__builtin_shufflevector(G##x, G##x, 0, 1),                  \
             __builtin_shufflevector(G##y, G##y, 0, 1),                  \
             __builtin_shufflevector(G##z, G##z, 0, 1),                  \
             __builtin_shufflevector(G##w, G##w, 0, 1))                  \
    PAIRSTEP(__builtin_shufflevector(G##x, G##x, 2, 3),                  \
             __builtin_shufflevector(G##y, G##y, 2, 3),                  \
             __builtin_shufflevector(G##z, G##z, 2, 3),                  \
             __builtin_shufflevector(G##w, G##w, 2, 3))

template <bool USE_ATOMIC>
__global__ __launch_bounds__(NTHR, 4) void chamfer_pass(
        const float* __restrict__ X, const float* __restrict__ Y,
        float* __restrict__ part, int* __restrict__ mins) {
    // grid = 2048: dir(2) x batch(4) x xtile(4) x ychunk(64)
    int bid = blockIdx.x;
    int dir = bid >> 10;
    int r   = bid & 1023;
    int b   = r >> 8;
    int rem = r & 255;
    int xt  = rem >> 6;
    int yc  = rem & 63;

    const float* src   = dir ? Y : X;   // cloud we take mins FOR
    const float* other = dir ? X : Y;   // cloud we min OVER

    __shared__ __align__(16) float lyx[YC], lyy[YC], lyz[YC], lyw[YC];
    int t = threadIdx.x;

    // stage 1 y-point per thread from raw interleaved xyz; SoA in LDS
    {
        const float* yb = other + ((size_t)b * NPTS + (size_t)yc * YC + t) * 3;
        float ax = yb[0], ay = yb[1], az = yb[2];
        lyx[t] = ax; lyy[t] = ay; lyz[t] = az;
        lyw[t] = __fmaf_rn(ax, ax, __fmaf_rn(ay, ay, az * az));
    }
    __syncthreads();

    // XR x-points in regs, pre-scaled by -2, splatted for pk_fma
    v2f xs[XR], ys[XR], zs[XR];
    float mn[XR];
    const float* xb = src + ((size_t)b * NPTS + (size_t)xt * XPB) * 3;
#pragma unroll
    for (int k = 0; k < XR; k++) {
        int xi = k * NTHR + t;
        float a = -2.0f * xb[3 * xi + 0];
        float bb = -2.0f * xb[3 * xi + 1];
        float c = -2.0f * xb[3 * xi + 2];
        xs[k] = (v2f){a, a};
        ys[k] = (v2f){bb, bb};
        zs[k] = (v2f){c, c};
        mn[k] = 3.0e38f;
    }

    // 32 register-groups of 4 y-points, A/B software pipeline
    v4f Ax, Ay, Az, Aw, Bx, By, Bz, Bw;
    LOADG(A, 0);
    for (int g = 0; g < (YC / 4 - 2); g += 2) {
        LOADG(B, g + 1);
        COMPUTEG(A);
        LOADG(A, g + 2);
        COMPUTEG(B);
    }
    LOADG(B, YC / 4 - 1);
    COMPUTEG(A);
    COMPUTEG(B);

    if (USE_ATOMIC) {
        int* om = mins + (dir ? NPTOT : 0) + (size_t)b * NPTS + (size_t)xt * XPB;
#pragma unroll
        for (int k = 0; k < XR; k++)
            atomicMin(&om[k * NTHR + t], f2key(mn[k]));
    } else {
        float* op = part + ((size_t)(dir * YCHUNKS + yc)) * NPTOT
                  + (size_t)b * NPTS + (size_t)xt * XPB;
#pragma unroll
        for (int k = 0; k < XR; k++)
            op[k * NTHR + t] = mn[k];
    }
}

template <bool USE_ATOMIC>
__global__ __launch_bounds__(256) void reduce1(
        const float* __restrict__ part, const int* __restrict__ mins,
        const float* __restrict__ X, const float* __restrict__ Y,
        float2* __restrict__ out2) {
    __shared__ float s1[256], s2[256];
    int t = threadIdx.x;
    float sx = 0.f, sy = 0.f;
    for (int i = blockIdx.x * 256 + t; i < NPTOT; i += RBLK * 256) {
        float mx, my;
        if (USE_ATOMIC) {
            mx = key2f(mins[i]);
            my = key2f(mins[NPTOT + i]);
        } else {
            mx = 3.0e38f; my = 3.0e38f;
#pragma unroll
            for (int c = 0; c < YCHUNKS; c++) {
                mx = fminf(mx, part[(size_t)c * NPTOT + i]);
                my = fminf(my, part[(size_t)(YCHUNKS + c) * NPTOT + i]);
            }
        }
        float a = X[3 * i], bb = X[3 * i + 1], c = X[3 * i + 2];
        sx += mx + __fmaf_rn(a, a, __fmaf_rn(bb, bb, c * c));
        float d = Y[3 * i], e = Y[3 * i + 1], f = Y[3 * i + 2];
        sy += my + __fmaf_rn(d, d, __fmaf_rn(e, e, f * f));
    }
    s1[t] = sx; s2[t] = sy;
    __syncthreads();
    for (int s = 128; s > 0; s >>= 1) {
        if (t < s) { s1[t] += s1[t + s]; s2[t] += s2[t + s]; }
        __syncthreads();
    }
    if (t == 0) out2[blockIdx.x] = make_float2(s1[0], s2[0]);
}

__global__ __launch_bounds__(RBLK) void reduce2(
        const float2* __restrict__ p2,
        const float* __restrict__ bpp, const float* __restrict__ lam,
        float* __restrict__ out) {
    __shared__ float s[RBLK];
    int t = threadIdx.x;
    float2 p = p2[t];
    s[t] = p.x + p.y;
    __syncthreads();
    for (int h = RBLK / 2; h > 0; h >>= 1) {
        if (t < h) s[t] += s[t + h];
        __syncthreads();
    }
    if (t == 0) out[0] = s[0] * (1.0f / (float)NPTOT) + lam[0] * bpp[0];
}

extern "C" void kernel_launch(void* const* d_in, const int* in_sizes, int n_in,
                              void* d_out, int out_size, void* d_ws, size_t ws_size,
                              hipStream_t stream) {
    const float* X   = (const float*)d_in[0];   // pc_pred  [4,8192,3]
    const float* Y   = (const float*)d_in[1];   // pc_target[4,8192,3]
    const float* bpp = (const float*)d_in[2];
    const float* lam = (const float*)d_in[3];
    float* out = (float*)d_out;

    char* w = (char*)d_ws;
    float2* p2 = (float2*)w;            // RBLK float2 partials (1 KB)
    char* w2 = w + 1024;

    size_t need_store = (size_t)2 * YCHUNKS * NPTOT * sizeof(float);  // 16.8 MB
    bool use_atomic = (ws_size < 1024 + need_store);

    if (use_atomic) {
        int* mins = (int*)w2;
        init_min<<<(2 * NPTOT + 255) / 256, 256, 0, stream>>>(mins);
        chamfer_pass<true><<<GRID, NTHR, 0, stream>>>(X, Y, nullptr, mins);
        reduce1<true><<<RBLK, 256, 0, stream>>>(nullptr, mins, X, Y, p2);
    } else {
        float* part = (float*)w2;
        chamfer_pass<false><<<GRID, NTHR, 0, stream>>>(X, Y, part, nullptr);
        reduce1<false><<<RBLK, 256, 0, stream>>>(part, nullptr, X, Y, p2);
    }
    reduce2<<<1, RBLK, 0, stream>>>(p2, bpp, lam, out);
}

// Round 7
// 40.621 us; speedup vs baseline: 9.2376x; 9.2376x over previous
//
#include <hip/hip_runtime.h>

// Chamfer loss: B=4, N=M=8192, D=3, fp32 in, scalar fp32 out.
// loss = mean_n min_m ||x_n-y_m||^2 + mean_m min_n ||...||^2 + lambda*bpp
//
// R6: MFMA formulation. Any FMA version needs >=3 VALU mults/pair (pinned
// ~44us); the matrix pipe removes them. d2 = x2 + (y2 - 2 x.y), and
// P = y2 - 2 x.y is computed by ONE v_mfma_f32_32x32x16_bf16 per 32x32
// tile using split-bf16 products (error ~2^-17 << 5.7e-3 threshold):
//   k0-2 : (-2 xhi_d) * (yhi_d)
//   k3   : (1)        * (y2hi)
//   k4-6 : (-2 xlo_d) * (yhi_d)
//   k7   : (1)        * (y2lo)
//   k8-10: (-2 xhi_d) * (ylo_d)     k11-15: 0
// Per-point 2x16B records (A-side and B-side) precomputed by prep.
// Two symmetric passes (dir 0/1) in one kernel: each wave owns 32 rows,
// streams 256 col-tiles (coalesced 16B/lane from L2), keeps 16-reg
// running min (1 VALU min per output = 6.8us floor), then 5 shfl_xor
// levels finish the row-min in-wave -> plain stores, no atomics.

typedef float  f16v __attribute__((ext_vector_type(16)));
typedef short  s8   __attribute__((ext_vector_type(8)));

#define NPTS   8192
#define NB     4
#define NPTOT  (NB * NPTS)        // 32768 points per cloud
#define JT     (NPTS / 32)        // 256 col-tiles per pass
#define RBLK   128

__device__ __forceinline__ ushort f2bf(float f) {
    uint u = __float_as_uint(f);
    u += 0x7FFF + ((u >> 16) & 1);          // round-to-nearest-even
    return (ushort)(u >> 16);
}
__device__ __forceinline__ float bf2f(ushort h) {
    return __uint_as_float(((uint)h) << 16);
}
__device__ __forceinline__ uint pk(ushort lo, ushort hi) {
    return (uint)lo | ((uint)hi << 16);
}

// prep: per point (both clouds): split coords and ||p||^2 into bf16 hi/lo,
// store A-side records (rows) and B-side records (cols), 2 x uint4 each.
__global__ __launch_bounds__(256) void prep(
        const float* __restrict__ X, const float* __restrict__ Y,
        uint4* __restrict__ Arec, uint4* __restrict__ Brec) {
    int i = blockIdx.x * 256 + threadIdx.x;
    if (i >= 2 * NPTOT) return;
    const float* src = (i < NPTOT) ? X : Y;
    int p = i & (NPTOT - 1);
    float x0 = src[3*p], x1 = src[3*p+1], x2 = src[3*p+2];
    float n2 = __fmaf_rn(x0, x0, __fmaf_rn(x1, x1, x2 * x2));

    ushort h0 = f2bf(x0), h1 = f2bf(x1), h2 = f2bf(x2);
    ushort l0 = f2bf(x0 - bf2f(h0));
    ushort l1 = f2bf(x1 - bf2f(h1));
    ushort l2 = f2bf(x2 - bf2f(h2));
    ushort n2h = f2bf(n2);
    ushort n2l = f2bf(n2 - bf2f(n2h));
    // -2*hi / -2*lo are exact in bf16
    ushort a0 = f2bf(-2.0f * bf2f(h0)), a1 = f2bf(-2.0f * bf2f(h1));
    ushort a2 = f2bf(-2.0f * bf2f(h2));
    ushort b0 = f2bf(-2.0f * bf2f(l0)), b1 = f2bf(-2.0f * bf2f(l1));
    ushort b2 = f2bf(-2.0f * bf2f(l2));
    const ushort ONE = 0x3F80;

    // A-side: k0-7 = [-2hi0,-2hi1,-2hi2, 1, -2lo0,-2lo1,-2lo2, 1]
    //         k8-15 = [-2hi0,-2hi1,-2hi2, 0,0,0,0,0]
    Arec[(size_t)i*2 + 0] = make_uint4(pk(a0,a1), pk(a2,ONE), pk(b0,b1), pk(b2,ONE));
    Arec[(size_t)i*2 + 1] = make_uint4(pk(a0,a1), pk(a2,0),   0,          0);
    // B-side: k0-7 = [hi0,hi1,hi2, n2hi, hi0,hi1,hi2, n2lo]
    //         k8-15 = [lo0,lo1,lo2, 0,0,0,0,0]
    Brec[(size_t)i*2 + 0] = make_uint4(pk(h0,h1), pk(h2,n2h), pk(h0,h1), pk(h2,n2l));
    Brec[(size_t)i*2 + 1] = make_uint4(pk(l0,l1), pk(l2,0),   0,          0);
}

#define LOADG(G, g)                                                        \
    _Pragma("unroll")                                                      \
    for (int u = 0; u < 4; u++)                                            \
        G[u] = *(const s8*)(Bb + (size_t)((g) * 4 + u) * 64 + boff);

#define COMPG(G)                                                           \
    _Pragma("unroll")                                                      \
    for (int u = 0; u < 4; u++) {                                          \
        f16v acc = __builtin_amdgcn_mfma_f32_32x32x16_bf16(                \
            afrag, G[u], zero16, 0, 0, 0);                                 \
        _Pragma("unroll")                                                  \
        for (int q = 0; q < 16; q++) racc[q] = fminf(racc[q], acc[q]);     \
    }

__global__ __launch_bounds__(256) void mfma_pass(
        const uint4* __restrict__ Arec, const uint4* __restrict__ Brec,
        float* __restrict__ mins) {
    // grid = 512: pass(2) x batch(4) x blk(64); 4 waves/block, 32 rows/wave
    int bid  = blockIdx.x;
    int pass = bid >> 8;            // 0: rows=X cols=Y; 1: rows=Y cols=X
    int r    = bid & 255;
    int b    = r >> 6;
    int blk  = r & 63;
    int lane = threadIdx.x & 63;
    int wave = threadIdx.x >> 6;
    int ca   = pass;                // A-cloud: 0=X,1=Y
    int cb   = 1 - pass;
    int ibase = (blk * 4 + wave) * 32;

    // A fragment: lane&31 = row, lane>>5 = k-half (record index)
    int pA = b * NPTS + ibase + (lane & 31);
    s8 afrag = *(const s8*)&Arec[((size_t)ca * NPTOT + pA) * 2 + (lane >> 5)];

    const uint4* Bb = Brec + ((size_t)cb * NPTOT + (size_t)b * NPTS) * 2;
    int boff = (lane & 31) * 2 + (lane >> 5);   // col = lane&31, rec = lane>>5

    const f16v zero16 = {0,0,0,0,0,0,0,0,0,0,0,0,0,0,0,0};
    f16v racc;
#pragma unroll
    for (int q = 0; q < 16; q++) racc[q] = 3.0e38f;

    // 64 groups of 4 col-tiles, ping-pong prefetch
    s8 GA[4], GB[4];
    LOADG(GA, 0);
    for (int g = 0; g < 62; g += 2) {
        LOADG(GB, g + 1);
        COMPG(GA);
        LOADG(GA, g + 2);
        COMPG(GB);
    }
    LOADG(GB, 63);
    COMPG(GA);
    COMPG(GB);

    // row-min across the 32 cols (lane bits 0-4), rows stay fixed
#pragma unroll
    for (int q = 0; q < 16; q++) {
        float v = racc[q];
        v = fminf(v, __shfl_xor(v, 1, 64));
        v = fminf(v, __shfl_xor(v, 2, 64));
        v = fminf(v, __shfl_xor(v, 4, 64));
        v = fminf(v, __shfl_xor(v, 8, 64));
        v = fminf(v, __shfl_xor(v, 16, 64));
        racc[q] = v;
    }
    if ((lane & 31) == 0) {
        float* dst = mins + (size_t)pass * NPTOT + b * NPTS + ibase;
        int half = lane >> 5;       // row offset +4 for lanes 32..63
#pragma unroll
        for (int q = 0; q < 16; q++)
            dst[(q & 3) + 8 * (q >> 2) + 4 * half] = racc[q];
    }
}

__global__ __launch_bounds__(256) void reduce1(
        const float* __restrict__ mins,
        const float* __restrict__ X, const float* __restrict__ Y,
        float2* __restrict__ out2) {
    __shared__ float s1[256], s2[256];
    int t = threadIdx.x;
    int i = blockIdx.x * 256 + t;           // RBLK*256 == NPTOT exactly
    float a = X[3*i], bb = X[3*i+1], c = X[3*i+2];
    float sx = mins[i] + __fmaf_rn(a, a, __fmaf_rn(bb, bb, c * c));
    float d = Y[3*i], e = Y[3*i+1], f = Y[3*i+2];
    float sy = mins[NPTOT + i] + __fmaf_rn(d, d, __fmaf_rn(e, e, f * f));
    s1[t] = sx; s2[t] = sy;
    __syncthreads();
    for (int s = 128; s > 0; s >>= 1) {
        if (t < s) { s1[t] += s1[t + s]; s2[t] += s2[t + s]; }
        __syncthreads();
    }
    if (t == 0) out2[blockIdx.x] = make_float2(s1[0], s2[0]);
}

__global__ __launch_bounds__(RBLK) void reduce2(
        const float2* __restrict__ p2,
        const float* __restrict__ bpp, const float* __restrict__ lam,
        float* __restrict__ out) {
    __shared__ float s[RBLK];
    int t = threadIdx.x;
    float2 p = p2[t];
    s[t] = p.x + p.y;
    __syncthreads();
    for (int h = RBLK / 2; h > 0; h >>= 1) {
        if (t < h) s[t] += s[t + h];
        __syncthreads();
    }
    if (t == 0) out[0] = s[0] * (1.0f / (float)NPTOT) + lam[0] * bpp[0];
}

extern "C" void kernel_launch(void* const* d_in, const int* in_sizes, int n_in,
                              void* d_out, int out_size, void* d_ws, size_t ws_size,
                              hipStream_t stream) {
    const float* X   = (const float*)d_in[0];   // pc_pred  [4,8192,3]
    const float* Y   = (const float*)d_in[1];   // pc_target[4,8192,3]
    const float* bpp = (const float*)d_in[2];
    const float* lam = (const float*)d_in[3];
    float* out = (float*)d_out;

    char* w = (char*)d_ws;
    float2* p2   = (float2*)w;                          w += 1024;
    float*  mins = (float*)w;                           w += 2 * NPTOT * sizeof(float);
    uint4*  Arec = (uint4*)w;                           w += (size_t)2 * NPTOT * 2 * sizeof(uint4);
    uint4*  Brec = (uint4*)w;

    prep<<<(2 * NPTOT + 255) / 256, 256, 0, stream>>>(X, Y, Arec, Brec);
    mfma_pass<<<512, 256, 0, stream>>>(Arec, Brec, mins);
    reduce1<<<RBLK, 256, 0, stream>>>(mins, X, Y, p2);
    reduce2<<<1, RBLK, 0, stream>>>(p2, bpp, lam, out);
}